// Round 16
// baseline (48.089 us; speedup 1.0000x reference)
//
#include <hip/hip_runtime.h>

#define DD 2048
#define MHH 32

typedef _Float16 hf2 __attribute__((ext_vector_type(2)));

__device__ __forceinline__ unsigned pack_pair(float lo, float hi) {
    hf2 v;
    v.x = (_Float16)lo;
    v.y = (_Float16)hi;
    return __builtin_bit_cast(unsigned, v);
}

__device__ __forceinline__ hf2 rfl2(unsigned u) {
    u = __builtin_amdgcn_readfirstlane(u);     // force SGPR residency
    return __builtin_bit_cast(hf2, u);
}

__device__ __forceinline__ hf2 dup16(float x) {
    hf2 v;
    v.x = (_Float16)x;
    v.y = v.x;
    return v;
}

// One kernel does EVERYTHING for one layer: block = 2 rows.
//  Phase 1: ov = relu(W_row . inp + b_row) via per-thread partial dots on the
//           same W/input registers meta needs + ONE block reduce. ov IS the
//           next layer's activation -> stored to aout. The gemv chain is gone.
//  Phase 2: nW[row, :] = bm2 + sum_m V2[m]*relu(u*A + w*B + (bm1 + ov*C)),
//           f16-packed over m-pairs, f32 accumulate via v_dot2_f32_f16.
// RAW=true (layer 1): meta constants packed from raw f32 (cst not ready yet);
//           block 0 additionally packs cst for the later layers.
// RAW=false (layers 2,3): constants from pre-packed cst.
// 1024 blocks x 256 threads, 4 blocks/CU -> exactly co-resident, one round.
template <bool RAW>
__global__ __launch_bounds__(256, 4) void fusedmeta_k(const float* __restrict__ W,
                                                      const float* __restrict__ bvec,
                                                      const float* __restrict__ inp,
                                                      float* __restrict__ aout,
                                                      float* __restrict__ nWl,
                                                      const float* __restrict__ Wm1,
                                                      const float* __restrict__ bm1,
                                                      const float* __restrict__ Wm2,
                                                      const float* __restrict__ bm2,
                                                      const unsigned* __restrict__ cst,
                                                      unsigned* __restrict__ cst_out) {
    // Fold the cst-packing into block 0 of the layer-1 dispatch (16 threads).
    if (RAW) {
        if (blockIdx.x == 0 && threadIdx.x < MHH / 2) {
            const int m = 2 * threadIdx.x;
            cst_out[threadIdx.x]      = pack_pair(Wm1[m],           Wm1[m + 1]);
            cst_out[16 + threadIdx.x] = pack_pair(Wm1[MHH + m],     Wm1[MHH + m + 1]);
            cst_out[32 + threadIdx.x] = pack_pair(Wm2[m],           Wm2[m + 1]);
            cst_out[48 + threadIdx.x] = pack_pair(Wm1[2 * MHH + m], Wm1[2 * MHH + m + 1]);
            cst_out[64 + threadIdx.x] = pack_pair(bm1[m],           bm1[m + 1]);
        }
    }

    const int row0 = blockIdx.x << 1;            // two consecutive rows
    const int wave = threadIdx.x >> 6;
    const int lane = threadIdx.x & 63;

    const float* Wr0 = W + (size_t)row0 * DD;
    const float* Wr1 = Wr0 + DD;
    float* nWr0 = nWl + (size_t)row0 * DD;
    float* nWr1 = nWr0 + DD;

    const int col0 = threadIdx.x * 4;            // first half, coalesced float4
    const int col1 = (DD / 2) + threadIdx.x * 4; // second half

    // All vector loads up front.
    const float4 u4a = *reinterpret_cast<const float4*>(inp + col0);
    const float4 u4b = *reinterpret_cast<const float4*>(inp + col1);
    const float4 w0a = *reinterpret_cast<const float4*>(Wr0 + col0);
    const float4 w0b = *reinterpret_cast<const float4*>(Wr0 + col1);
    const float4 w1a = *reinterpret_cast<const float4*>(Wr1 + col0);
    const float4 w1b = *reinterpret_cast<const float4*>(Wr1 + col1);
    const float2 bb  = *reinterpret_cast<const float2*>(bvec + row0);

    // ---- Phase 1: both rows' dots, one reduce, one barrier ----
    float p0 = 0.f, p1 = 0.f;
    p0 = fmaf(w0a.x, u4a.x, p0); p0 = fmaf(w0a.y, u4a.y, p0);
    p0 = fmaf(w0a.z, u4a.z, p0); p0 = fmaf(w0a.w, u4a.w, p0);
    p0 = fmaf(w0b.x, u4b.x, p0); p0 = fmaf(w0b.y, u4b.y, p0);
    p0 = fmaf(w0b.z, u4b.z, p0); p0 = fmaf(w0b.w, u4b.w, p0);
    p1 = fmaf(w1a.x, u4a.x, p1); p1 = fmaf(w1a.y, u4a.y, p1);
    p1 = fmaf(w1a.z, u4a.z, p1); p1 = fmaf(w1a.w, u4a.w, p1);
    p1 = fmaf(w1b.x, u4b.x, p1); p1 = fmaf(w1b.y, u4b.y, p1);
    p1 = fmaf(w1b.z, u4b.z, p1); p1 = fmaf(w1b.w, u4b.w, p1);
#pragma unroll
    for (int off = 32; off > 0; off >>= 1) {
        p0 += __shfl_down(p0, off, 64);
        p1 += __shfl_down(p1, off, 64);
    }
    __shared__ float red[4][2];
    if (lane == 0) { red[wave][0] = p0; red[wave][1] = p1; }

    // ---- constants while the reduce settles ----
    hf2 Ap[MHH / 2], Bp[MHH / 2], Vp[MHH / 2], Cm[MHH / 2], Bm[MHH / 2];
    if (RAW) {
#pragma unroll
        for (int mp = 0; mp < MHH / 2; ++mp) {
            const int m = 2 * mp;
            Ap[mp] = rfl2(pack_pair(Wm1[m],           Wm1[m + 1]));
            Bp[mp] = rfl2(pack_pair(Wm1[MHH + m],     Wm1[MHH + m + 1]));
            Vp[mp] = rfl2(pack_pair(Wm2[m],           Wm2[m + 1]));
            Cm[mp] = rfl2(pack_pair(Wm1[2 * MHH + m], Wm1[2 * MHH + m + 1]));
            Bm[mp] = __builtin_bit_cast(hf2, pack_pair(bm1[m], bm1[m + 1]));
        }
    } else {
        const uint4* c16 = (const uint4*)cst;
#pragma unroll
        for (int j = 0; j < 4; ++j) {
            const uint4 t = c16[j];
            Ap[4 * j + 0] = rfl2(t.x); Ap[4 * j + 1] = rfl2(t.y);
            Ap[4 * j + 2] = rfl2(t.z); Ap[4 * j + 3] = rfl2(t.w);
        }
#pragma unroll
        for (int j = 0; j < 4; ++j) {
            const uint4 t = c16[4 + j];
            Bp[4 * j + 0] = rfl2(t.x); Bp[4 * j + 1] = rfl2(t.y);
            Bp[4 * j + 2] = rfl2(t.z); Bp[4 * j + 3] = rfl2(t.w);
        }
#pragma unroll
        for (int j = 0; j < 4; ++j) {
            const uint4 t = c16[8 + j];
            Vp[4 * j + 0] = rfl2(t.x); Vp[4 * j + 1] = rfl2(t.y);
            Vp[4 * j + 2] = rfl2(t.z); Vp[4 * j + 3] = rfl2(t.w);
        }
#pragma unroll
        for (int j = 0; j < 4; ++j) {
            const uint4 tc = c16[12 + j];
            const uint4 tb = c16[16 + j];
            Cm[4 * j + 0] = rfl2(tc.x); Cm[4 * j + 1] = rfl2(tc.y);
            Cm[4 * j + 2] = rfl2(tc.z); Cm[4 * j + 3] = rfl2(tc.w);
            Bm[4 * j + 0] = __builtin_bit_cast(hf2, tb.x);
            Bm[4 * j + 1] = __builtin_bit_cast(hf2, tb.y);
            Bm[4 * j + 2] = __builtin_bit_cast(hf2, tb.z);
            Bm[4 * j + 3] = __builtin_bit_cast(hf2, tb.w);
        }
    }
    const float bias2 = bm2[0];

    // Input dups (pinned — invariant across both rows and the m-loop).
    hf2 ud[8];
    ud[0] = dup16(u4a.x); ud[1] = dup16(u4a.y); ud[2] = dup16(u4a.z); ud[3] = dup16(u4a.w);
    ud[4] = dup16(u4b.x); ud[5] = dup16(u4b.y); ud[6] = dup16(u4b.z); ud[7] = dup16(u4b.w);
    asm volatile("" : "+v"(ud[0]), "+v"(ud[1]), "+v"(ud[2]), "+v"(ud[3]),
                      "+v"(ud[4]), "+v"(ud[5]), "+v"(ud[6]), "+v"(ud[7]));

    __syncthreads();
    const float ov0 = fmaxf(red[0][0] + red[1][0] + red[2][0] + red[3][0] + bb.x, 0.f);
    const float ov1 = fmaxf(red[0][1] + red[1][1] + red[2][1] + red[3][1] + bb.y, 0.f);
    if (threadIdx.x == 0) {
        aout[row0]     = ov0;                    // this IS the next activation
        aout[row0 + 1] = ov1;
    }

    const hf2 zero = (hf2)(_Float16)0.f;

    // ---- Phase 2: meta for the two rows ----
#pragma unroll
    for (int r = 0; r < 2; ++r) {
        const float4 wa = r ? w1a : w0a;
        const float4 wb = r ? w1b : w0b;
        const float ovr = r ? ov1 : ov0;

        hf2 wd[8];
        wd[0] = dup16(wa.x); wd[1] = dup16(wa.y); wd[2] = dup16(wa.z); wd[3] = dup16(wa.w);
        wd[4] = dup16(wb.x); wd[5] = dup16(wb.y); wd[6] = dup16(wb.z); wd[7] = dup16(wb.w);
        asm volatile("" : "+v"(wd[0]), "+v"(wd[1]), "+v"(wd[2]), "+v"(wd[3]),
                          "+v"(wd[4]), "+v"(wd[5]), "+v"(wd[6]), "+v"(wd[7]));

        const hf2 ovd = dup16(ovr);
        hf2 Pp[MHH / 2];
#pragma unroll
        for (int mp = 0; mp < MHH / 2; ++mp) {
            Pp[mp] = __builtin_elementwise_fma(ovd, Cm[mp], Bm[mp]);
            asm volatile("" : "+v"(Pp[mp]));    // keep P in VGPR
        }

        float c0 = bias2, c1 = bias2, c2 = bias2, c3 = bias2;
        float c4 = bias2, c5 = bias2, c6 = bias2, c7 = bias2;

#pragma unroll
        for (int mp = 0; mp < MHH / 2; ++mp) {
            const hf2 a = Ap[mp], b = Bp[mp], v = Vp[mp], p = Pp[mp];
            hf2 q0 = __builtin_elementwise_fma(ud[0], a, p);
            hf2 q1 = __builtin_elementwise_fma(ud[1], a, p);
            hf2 q2 = __builtin_elementwise_fma(ud[2], a, p);
            hf2 q3 = __builtin_elementwise_fma(ud[3], a, p);
            hf2 q4 = __builtin_elementwise_fma(ud[4], a, p);
            hf2 q5 = __builtin_elementwise_fma(ud[5], a, p);
            hf2 q6 = __builtin_elementwise_fma(ud[6], a, p);
            hf2 q7 = __builtin_elementwise_fma(ud[7], a, p);
            q0 = __builtin_elementwise_fma(wd[0], b, q0);
            q1 = __builtin_elementwise_fma(wd[1], b, q1);
            q2 = __builtin_elementwise_fma(wd[2], b, q2);
            q3 = __builtin_elementwise_fma(wd[3], b, q3);
            q4 = __builtin_elementwise_fma(wd[4], b, q4);
            q5 = __builtin_elementwise_fma(wd[5], b, q5);
            q6 = __builtin_elementwise_fma(wd[6], b, q6);
            q7 = __builtin_elementwise_fma(wd[7], b, q7);
            q0 = __builtin_elementwise_max(q0, zero);
            q1 = __builtin_elementwise_max(q1, zero);
            q2 = __builtin_elementwise_max(q2, zero);
            q3 = __builtin_elementwise_max(q3, zero);
            q4 = __builtin_elementwise_max(q4, zero);
            q5 = __builtin_elementwise_max(q5, zero);
            q6 = __builtin_elementwise_max(q6, zero);
            q7 = __builtin_elementwise_max(q7, zero);
            c0 = __builtin_amdgcn_fdot2(q0, v, c0, false);
            c1 = __builtin_amdgcn_fdot2(q1, v, c1, false);
            c2 = __builtin_amdgcn_fdot2(q2, v, c2, false);
            c3 = __builtin_amdgcn_fdot2(q3, v, c3, false);
            c4 = __builtin_amdgcn_fdot2(q4, v, c4, false);
            c5 = __builtin_amdgcn_fdot2(q5, v, c5, false);
            c6 = __builtin_amdgcn_fdot2(q6, v, c6, false);
            c7 = __builtin_amdgcn_fdot2(q7, v, c7, false);
        }

        float4 r0v, r1v;
        r0v.x = c0; r0v.y = c1; r0v.z = c2; r0v.w = c3;
        r1v.x = c4; r1v.y = c5; r1v.z = c6; r1v.w = c7;
        float* nWr = r ? nWr1 : nWr0;
        *reinterpret_cast<float4*>(nWr + col0) = r0v;
        *reinterpret_cast<float4*>(nWr + col1) = r1v;
    }
}

extern "C" void kernel_launch(void* const* d_in, const int* in_sizes, int n_in,
                              void* d_out, int out_size, void* d_ws, size_t ws_size,
                              hipStream_t stream) {
    const float* x   = (const float*)d_in[0];
    const float* W1  = (const float*)d_in[1];
    const float* b1  = (const float*)d_in[2];
    const float* W2  = (const float*)d_in[3];
    const float* b2  = (const float*)d_in[4];
    const float* W3  = (const float*)d_in[5];
    const float* b3  = (const float*)d_in[6];
    const float* Wm1 = (const float*)d_in[7];
    const float* bm1 = (const float*)d_in[8];
    const float* Wm2 = (const float*)d_in[9];
    const float* bm2 = (const float*)d_in[10];

    float* out = (float*)d_out;            // out: [2048]
    float* nW1 = out + DD;                 // nW1|nW2|nW3: 3 x 2048 x 2048
    float* nW2 = nW1 + (size_t)DD * DD;
    float* nW3 = nW2 + (size_t)DD * DD;
    float* a1  = (float*)d_ws;             // [2048]
    float* a2  = a1 + DD;                  // [2048]
    unsigned* cst = (unsigned*)(a2 + DD);  // [80] packed f16x2 constants

    // Layer 1: raw constants (also packs cst in block 0); writes a1 + nW1.
    fusedmeta_k<true><<<DD / 2, 256, 0, stream>>>(W1, b1, x, a1, nW1,
                                                  Wm1, bm1, Wm2, bm2,
                                                  nullptr, cst);
    // Layer 2: cst constants; writes a2 + nW2.
    fusedmeta_k<false><<<DD / 2, 256, 0, stream>>>(W2, b2, a1, a2, nW2,
                                                   Wm1, bm1, Wm2, bm2,
                                                   cst, nullptr);
    // Layer 3: cst constants; writes out + nW3.
    fusedmeta_k<false><<<DD / 2, 256, 0, stream>>>(W3, b3, a2, out, nW3,
                                                   Wm1, bm1, Wm2, bm2,
                                                   cst, nullptr);
}

// Round 17
// 45.877 us; speedup vs baseline: 1.0482x; 1.0482x over previous
//
#include <hip/hip_runtime.h>

#define DD 2048
#define MHH 32

typedef _Float16 hf2 __attribute__((ext_vector_type(2)));

__device__ __forceinline__ unsigned pack_pair(float lo, float hi) {
    hf2 v;
    v.x = (_Float16)lo;
    v.y = (_Float16)hi;
    return __builtin_bit_cast(unsigned, v);
}

__device__ __forceinline__ hf2 rfl2(unsigned u) {
    u = __builtin_amdgcn_readfirstlane(u);     // force SGPR residency
    return __builtin_bit_cast(hf2, u);
}

__device__ __forceinline__ hf2 dup16(float x) {
    hf2 v;
    v.x = (_Float16)x;
    v.y = v.x;
    return v;
}

// ---- gemv: 4 rows per block (one wave per row), y = relu(W x + b) ----
__device__ __forceinline__ void gemv4_body(const float* __restrict__ W,
                                           const float* __restrict__ x,
                                           const float* __restrict__ b,
                                           float* __restrict__ y, int blk) {
    const int wave = threadIdx.x >> 6;
    const int lane = threadIdx.x & 63;
    const int row  = (blk << 2) + wave;
    const float* Wr = W + (size_t)row * DD;
    float acc = 0.f;
#pragma unroll
    for (int it = 0; it < 8; ++it) {
        const int col = ((it << 6) + lane) << 2;       // float4 index, coalesced
        const float4 w4 = *reinterpret_cast<const float4*>(Wr + col);
        const float4 x4 = *reinterpret_cast<const float4*>(x + col);
        acc = fmaf(w4.x, x4.x, acc);
        acc = fmaf(w4.y, x4.y, acc);
        acc = fmaf(w4.z, x4.z, acc);
        acc = fmaf(w4.w, x4.w, acc);
    }
#pragma unroll
    for (int off = 32; off > 0; off >>= 1)
        acc += __shfl_down(acc, off, 64);
    if (lane == 0) {
        const float v = acc + b[row];
        y[row] = fmaxf(v, 0.f);
    }
}

// k1: gemv layer1 (blocks 0..511) + constant-packing block (block 512).
__global__ __launch_bounds__(256) void gemv_relu_prep_k(const float* __restrict__ W,
                                                        const float* __restrict__ x,
                                                        const float* __restrict__ b,
                                                        float* __restrict__ y,
                                                        const float* __restrict__ Wm1,
                                                        const float* __restrict__ bm1,
                                                        const float* __restrict__ Wm2,
                                                        unsigned* __restrict__ cst) {
    if (blockIdx.x == DD / 4) {
        const int mp = threadIdx.x;
        if (mp < MHH / 2) {
            const int m = 2 * mp;
            cst[mp]      = pack_pair(Wm1[m],           Wm1[m + 1]);            // A
            cst[16 + mp] = pack_pair(Wm1[MHH + m],     Wm1[MHH + m + 1]);      // B
            cst[32 + mp] = pack_pair(Wm2[m],           Wm2[m + 1]);            // V2
            cst[48 + mp] = pack_pair(Wm1[2 * MHH + m], Wm1[2 * MHH + m + 1]);  // C
            cst[64 + mp] = pack_pair(bm1[m],           bm1[m + 1]);            // bm1
        }
        return;
    }
    gemv4_body(W, x, b, y, blockIdx.x);
}

__global__ __launch_bounds__(256) void gemv_relu_k(const float* __restrict__ W,
                                                   const float* __restrict__ x,
                                                   const float* __restrict__ b,
                                                   float* __restrict__ y) {
    gemv4_body(W, x, b, y, blockIdx.x);
}

// meta: 1536 blocks (512 per layer), each block = FOUR consecutive rows of one
// layer. All blocks co-resident (6 blocks/CU at <=85 VGPR): constant setup,
// input load+dup done ONCE per block; per-row cost is 2 W float4 loads,
// 16 P-fmas, and the 512-instr packed inner loop.
__global__ __launch_bounds__(256, 6) void meta_k(const float* __restrict__ W1,
                                                 const float* __restrict__ W2,
                                                 const float* __restrict__ W3,
                                                 const float* __restrict__ a0,
                                                 const float* __restrict__ a1,
                                                 const float* __restrict__ a2,
                                                 const float* __restrict__ a3,
                                                 const unsigned* __restrict__ cst,
                                                 const float* __restrict__ bm2,
                                                 float* __restrict__ nW) {
    const int layer = blockIdx.x >> 9;           // 512 blocks per layer
    const int row0  = (blockIdx.x & 511) << 2;   // 4 consecutive rows

    const float* W   = (layer == 0) ? W1 : (layer == 1) ? W2 : W3;
    const float* inp = (layer == 0) ? a0 : (layer == 1) ? a1 : a2;
    const float* oup = (layer == 0) ? a1 : (layer == 1) ? a2 : a3;

    const float* Wr  = W  + (size_t)row0 * DD;
    float*       nWr = nW + (size_t)layer * DD * DD + (size_t)row0 * DD;

    const int col0 = threadIdx.x * 4;            // first half, coalesced float4
    const int col1 = (DD / 2) + threadIdx.x * 4; // second half

    // Shared (per-block) loads: input vector halves + the 4 output activations.
    const float4 u4a = *reinterpret_cast<const float4*>(inp + col0);
    const float4 u4b = *reinterpret_cast<const float4*>(inp + col1);
    const float4 ov4 = *reinterpret_cast<const float4*>(oup + row0);

    // ---- constants: A/B/V2/C -> SGPR, bm1 -> VGPR (once per block) ----
    const uint4* c16 = (const uint4*)cst;
    hf2 Ap[MHH / 2], Bp[MHH / 2], Vp[MHH / 2], Cm[MHH / 2], Bm[MHH / 2];
#pragma unroll
    for (int j = 0; j < 4; ++j) {
        const uint4 t = c16[j];
        Ap[4 * j + 0] = rfl2(t.x); Ap[4 * j + 1] = rfl2(t.y);
        Ap[4 * j + 2] = rfl2(t.z); Ap[4 * j + 3] = rfl2(t.w);
    }
#pragma unroll
    for (int j = 0; j < 4; ++j) {
        const uint4 t = c16[4 + j];
        Bp[4 * j + 0] = rfl2(t.x); Bp[4 * j + 1] = rfl2(t.y);
        Bp[4 * j + 2] = rfl2(t.z); Bp[4 * j + 3] = rfl2(t.w);
    }
#pragma unroll
    for (int j = 0; j < 4; ++j) {
        const uint4 t = c16[8 + j];
        Vp[4 * j + 0] = rfl2(t.x); Vp[4 * j + 1] = rfl2(t.y);
        Vp[4 * j + 2] = rfl2(t.z); Vp[4 * j + 3] = rfl2(t.w);
    }
#pragma unroll
    for (int j = 0; j < 4; ++j) {
        const uint4 tc = c16[12 + j];
        const uint4 tb = c16[16 + j];
        Cm[4 * j + 0] = rfl2(tc.x); Cm[4 * j + 1] = rfl2(tc.y);
        Cm[4 * j + 2] = rfl2(tc.z); Cm[4 * j + 3] = rfl2(tc.w);
        Bm[4 * j + 0] = __builtin_bit_cast(hf2, tb.x);
        Bm[4 * j + 1] = __builtin_bit_cast(hf2, tb.y);
        Bm[4 * j + 2] = __builtin_bit_cast(hf2, tb.z);
        Bm[4 * j + 3] = __builtin_bit_cast(hf2, tb.w);
    }
    const float bias2 = bm2[0];

    // Shared input dups (pinned — invariant across all 4 rows and the m-loop).
    hf2 ud[8];
    ud[0] = dup16(u4a.x); ud[1] = dup16(u4a.y); ud[2] = dup16(u4a.z); ud[3] = dup16(u4a.w);
    ud[4] = dup16(u4b.x); ud[5] = dup16(u4b.y); ud[6] = dup16(u4b.z); ud[7] = dup16(u4b.w);
    asm volatile("" : "+v"(ud[0]), "+v"(ud[1]), "+v"(ud[2]), "+v"(ud[3]),
                      "+v"(ud[4]), "+v"(ud[5]), "+v"(ud[6]), "+v"(ud[7]));

    const hf2 zero = (hf2)(_Float16)0.f;

#pragma unroll
    for (int r = 0; r < 4; ++r) {
        const float* Wrr = Wr + (size_t)r * DD;
        const float4 wa = *reinterpret_cast<const float4*>(Wrr + col0);
        const float4 wb = *reinterpret_cast<const float4*>(Wrr + col1);
        const float ovr = (r == 0) ? ov4.x : (r == 1) ? ov4.y : (r == 2) ? ov4.z : ov4.w;
        const hf2 ovd = dup16(ovr);

        hf2 Pp[MHH / 2];
#pragma unroll
        for (int mp = 0; mp < MHH / 2; ++mp) {
            Pp[mp] = __builtin_elementwise_fma(ovd, Cm[mp], Bm[mp]);
            asm volatile("" : "+v"(Pp[mp]));    // keep P in VGPR
        }

        hf2 wd[8];
        wd[0] = dup16(wa.x); wd[1] = dup16(wa.y); wd[2] = dup16(wa.z); wd[3] = dup16(wa.w);
        wd[4] = dup16(wb.x); wd[5] = dup16(wb.y); wd[6] = dup16(wb.z); wd[7] = dup16(wb.w);

        float c0 = bias2, c1 = bias2, c2 = bias2, c3 = bias2;
        float c4 = bias2, c5 = bias2, c6 = bias2, c7 = bias2;

#pragma unroll
        for (int mp = 0; mp < MHH / 2; ++mp) {
            const hf2 a = Ap[mp], b = Bp[mp], v = Vp[mp], p = Pp[mp];
            hf2 q0 = __builtin_elementwise_fma(ud[0], a, p);
            hf2 q1 = __builtin_elementwise_fma(ud[1], a, p);
            hf2 q2 = __builtin_elementwise_fma(ud[2], a, p);
            hf2 q3 = __builtin_elementwise_fma(ud[3], a, p);
            hf2 q4 = __builtin_elementwise_fma(ud[4], a, p);
            hf2 q5 = __builtin_elementwise_fma(ud[5], a, p);
            hf2 q6 = __builtin_elementwise_fma(ud[6], a, p);
            hf2 q7 = __builtin_elementwise_fma(ud[7], a, p);
            q0 = __builtin_elementwise_fma(wd[0], b, q0);
            q1 = __builtin_elementwise_fma(wd[1], b, q1);
            q2 = __builtin_elementwise_fma(wd[2], b, q2);
            q3 = __builtin_elementwise_fma(wd[3], b, q3);
            q4 = __builtin_elementwise_fma(wd[4], b, q4);
            q5 = __builtin_elementwise_fma(wd[5], b, q5);
            q6 = __builtin_elementwise_fma(wd[6], b, q6);
            q7 = __builtin_elementwise_fma(wd[7], b, q7);
            q0 = __builtin_elementwise_max(q0, zero);
            q1 = __builtin_elementwise_max(q1, zero);
            q2 = __builtin_elementwise_max(q2, zero);
            q3 = __builtin_elementwise_max(q3, zero);
            q4 = __builtin_elementwise_max(q4, zero);
            q5 = __builtin_elementwise_max(q5, zero);
            q6 = __builtin_elementwise_max(q6, zero);
            q7 = __builtin_elementwise_max(q7, zero);
            c0 = __builtin_amdgcn_fdot2(q0, v, c0, false);
            c1 = __builtin_amdgcn_fdot2(q1, v, c1, false);
            c2 = __builtin_amdgcn_fdot2(q2, v, c2, false);
            c3 = __builtin_amdgcn_fdot2(q3, v, c3, false);
            c4 = __builtin_amdgcn_fdot2(q4, v, c4, false);
            c5 = __builtin_amdgcn_fdot2(q5, v, c5, false);
            c6 = __builtin_amdgcn_fdot2(q6, v, c6, false);
            c7 = __builtin_amdgcn_fdot2(q7, v, c7, false);
        }

        float4 r0, r1;
        r0.x = c0; r0.y = c1; r0.z = c2; r0.w = c3;
        r1.x = c4; r1.y = c5; r1.z = c6; r1.w = c7;
        float* nWrr = nWr + (size_t)r * DD;
        *reinterpret_cast<float4*>(nWrr + col0) = r0;
        *reinterpret_cast<float4*>(nWrr + col1) = r1;
    }
}

extern "C" void kernel_launch(void* const* d_in, const int* in_sizes, int n_in,
                              void* d_out, int out_size, void* d_ws, size_t ws_size,
                              hipStream_t stream) {
    const float* x   = (const float*)d_in[0];
    const float* W1  = (const float*)d_in[1];
    const float* b1  = (const float*)d_in[2];
    const float* W2  = (const float*)d_in[3];
    const float* b2  = (const float*)d_in[4];
    const float* W3  = (const float*)d_in[5];
    const float* b3  = (const float*)d_in[6];
    const float* Wm1 = (const float*)d_in[7];
    const float* bm1 = (const float*)d_in[8];
    const float* Wm2 = (const float*)d_in[9];
    const float* bm2 = (const float*)d_in[10];

    float* out = (float*)d_out;            // out: [2048]
    float* nW  = out + DD;                 // nW1|nW2|nW3: 3 x 2048 x 2048
    float* a1  = (float*)d_ws;             // [2048]
    float* a2  = a1 + DD;                  // [2048]
    unsigned* cst = (unsigned*)(a2 + DD);  // [80] packed f16x2 constants

    gemv_relu_prep_k<<<DD / 4 + 1, 256, 0, stream>>>(W1, x, b1, a1, Wm1, bm1, Wm2, cst);
    gemv_relu_k<<<DD / 4, 256, 0, stream>>>(W2, a1, b2, a2);
    gemv_relu_k<<<DD / 4, 256, 0, stream>>>(W3, a2, b3, out);
    meta_k<<<3 * DD / 4, 256, 0, stream>>>(W1, W2, W3, x, a1, a2, out,
                                           cst, bm2, nW);
}